// Round 4
// baseline (492.736 us; speedup 1.0000x reference)
//
#include <hip/hip_runtime.h>
#include <hip/hip_fp16.h>
#include <stdint.h>

#define TS 200

typedef _Float16 h2_t  __attribute__((ext_vector_type(2)));
typedef _Float16 f16x8 __attribute__((ext_vector_type(8)));
typedef float    f32x4 __attribute__((ext_vector_type(4)));

static __device__ __forceinline__ float fdot2f(uint32_t w, uint32_t h, float acc) {
#if __has_builtin(__builtin_amdgcn_fdot2)
    return __builtin_amdgcn_fdot2(__builtin_bit_cast(h2_t, w),
                                  __builtin_bit_cast(h2_t, h), acc, false);
#else
    h2_t a = __builtin_bit_cast(h2_t, w), b = __builtin_bit_cast(h2_t, h);
    acc = fmaf((float)a.x, (float)b.x, acc);
    acc = fmaf((float)a.y, (float)b.y, acc);
    return acc;
#endif
}

template <int CTRL>
static __device__ __forceinline__ float dpp_add(float x) {
    int m = __builtin_amdgcn_update_dpp(0, __builtin_bit_cast(int, x), CTRL, 0xF, 0xF, true);
    return x + __builtin_bit_cast(float, m);
}
template <int CTRL>
static __device__ __forceinline__ float dpp_mov(float x) {
    int m = __builtin_amdgcn_update_dpp(0, __builtin_bit_cast(int, x), CTRL, 0xF, 0xF, true);
    return __builtin_bit_cast(float, m);
}

// ---------------------------------------------------------------------------
// K0: one-time packs (unchanged).
// ---------------------------------------------------------------------------
__global__ __launch_bounds__(256) void pack_all(const float* __restrict__ x,
                                                const float* __restrict__ Wx,
                                                const float* __restrict__ Wh,
                                                _Float16* __restrict__ xh,
                                                _Float16* __restrict__ wxt,
                                                uint32_t* __restrict__ wp) {
    int bid = blockIdx.x, tid = threadIdx.x;
    if (bid < 6400) {
        int row = bid, col = tid;
        int b = row / 200, t = row - b * 200;
        xh[(size_t)row * 256 + col] = (_Float16)x[((size_t)(b * 2000 + t * 10)) * 256 + col];
    } else if (bid < 8448) {
        int n = bid - 6400, k = tid;
        wxt[(size_t)n * 256 + k] = (_Float16)Wx[((size_t)((n >> 8) * 256 + k)) * 256 + (n & 255)];
    } else {
        int idx = (bid - 8448) * 256 + tid;          // [0, 262144)
        int e   = idx & 3;
        int thr = (idx >> 2) & 1023;
        int j   = (idx >> 12) & 15;
        int c   = idx >> 16;
        int a = j >> 2, i = j & 3;
        int uu = a >> 1, g = a & 1;
        int vs = thr & 7, uq = (thr >> 3) & 7, wv = thr >> 6;
        int u = (wv * 8 + uq) * 2 + uu;
        int v = vs * 32 + i * 8 + e * 2;
        const float* base = Wh + ((size_t)((c * 2 + g) * 256 + v)) * 256 + u;
        h2_t p; p.x = (_Float16)base[0]; p.y = (_Float16)base[256];
        wp[idx] = __builtin_bit_cast(uint32_t, p);
    }
}

// ---------------------------------------------------------------------------
// K1: xp = X[6400x256] * W[256x2048] + bias, f16 MFMA 16x16x32. (unchanged)
// ---------------------------------------------------------------------------
__global__ __launch_bounds__(256) void xp_gemm(const _Float16* __restrict__ xh,
                                               const _Float16* __restrict__ wxt,
                                               const float* __restrict__ bxf,
                                               _Float16* __restrict__ xp) {
    __shared__ _Float16 As[128 * 64];
    __shared__ _Float16 Bs[128 * 64];
    const int tid = threadIdx.x;
    const int lane = tid & 63, w = tid >> 6;
    const int m0 = (blockIdx.x >> 4) * 128;
    const int n0 = (blockIdx.x & 15) * 128;
    const int mw = (w & 1) * 64, nw = (w >> 1) * 64;

    f32x4 acc[4][4] = {};

    for (int kb = 0; kb < 4; kb++) {
        const int k0 = kb * 64;
#pragma unroll
        for (int q = 0; q < 4; q++) {
            int ii = w * 4 + q;
            int r = ii * 8 + (lane >> 3);
            int kcol = (lane & 7) * 8;
            const _Float16* ga = xh  + (size_t)(m0 + r) * 256 + k0 + kcol;
            const _Float16* gb = wxt + (size_t)(n0 + r) * 256 + k0 + kcol;
            __builtin_amdgcn_global_load_lds(
                (const __attribute__((address_space(1))) uint32_t*)ga,
                (__attribute__((address_space(3))) uint32_t*)(As + ii * 512), 16, 0, 0);
            __builtin_amdgcn_global_load_lds(
                (const __attribute__((address_space(1))) uint32_t*)gb,
                (__attribute__((address_space(3))) uint32_t*)(Bs + ii * 512), 16, 0, 0);
        }
        __syncthreads();
#pragma unroll
        for (int kc = 0; kc < 2; kc++) {
            f16x8 a[4], b[4];
#pragma unroll
            for (int mt = 0; mt < 4; mt++)
                a[mt] = *(const f16x8*)&As[(mw + mt * 16 + (lane & 15)) * 64 + kc * 32 + (lane >> 4) * 8];
#pragma unroll
            for (int nt = 0; nt < 4; nt++)
                b[nt] = *(const f16x8*)&Bs[(nw + nt * 16 + (lane & 15)) * 64 + kc * 32 + (lane >> 4) * 8];
#pragma unroll
            for (int mt = 0; mt < 4; mt++)
#pragma unroll
                for (int nt = 0; nt < 4; nt++)
                    acc[mt][nt] = __builtin_amdgcn_mfma_f32_16x16x32_f16(a[mt], b[nt], acc[mt][nt], 0, 0, 0);
        }
        __syncthreads();
    }

    const int nl = lane & 15, quad = lane >> 4;
#pragma unroll
    for (int nt = 0; nt < 4; nt++) {
        int n = n0 + nw + nt * 16 + nl;
        float bias = bxf[n];
        int c = n >> 9, gu = n & 511;
#pragma unroll
        for (int mt = 0; mt < 4; mt++)
#pragma unroll
            for (int r = 0; r < 4; r++) {
                int m = m0 + mw + mt * 16 + quad * 4 + r;
                int b = m / 200, t = m - b * 200;
                xp[((size_t)((c * 32 + b) * 200 + t)) * 512 + gu] =
                    (_Float16)(acc[mt][nt][r] + bias);
            }
    }
}

// ---------------------------------------------------------------------------
// K2: 200-step gated recurrence. R4: 64 WGs x 512 threads; each WG runs TWO
// independent (c,b) recurrences with the SAME c: pair P=(c,b0), Q=(c,b0+16).
// Weights (128 pinned VGPRs) are shared; h-state/xp/accs duplicate. One
// barrier per time-step covers both pairs -> the fixed per-step latency
// (ds_read, dpp/exp tails, lgkm ack, barrier wake ~1600cy, invariant in
// R0/R1/R2) amortizes over 2 steps of work, and each latency element has
// the other pair's independent instructions to hide under (16 dot chains).
// Sync = R2's proven LDS-only barrier (R3's flag-poll regressed; reverted).
// ---------------------------------------------------------------------------
#define D4(ACC, W, H)                 \
    ACC = fdot2f(W.x, H.x, ACC);      \
    ACC = fdot2f(W.y, H.y, ACC);      \
    ACC = fdot2f(W.z, H.z, ACC);      \
    ACC = fdot2f(W.w, H.w, ACC);

#define PIN4(W) asm volatile("" : "+v"(W.x), "+v"(W.y), "+v"(W.z), "+v"(W.w))

#define RED3(A) A = dpp_add<0x141>(dpp_add<0x4E>(dpp_add<0xB1>(A)));

#define LDS_BARRIER()                                        \
    do {                                                     \
        __builtin_amdgcn_sched_barrier(0);                   \
        asm volatile("s_waitcnt lgkmcnt(0)" ::: "memory");   \
        __builtin_amdgcn_s_barrier();                        \
        __builtin_amdgcn_sched_barrier(0);                   \
    } while (0)

__global__ __attribute__((amdgpu_flat_work_group_size(512, 512),
                          amdgpu_waves_per_eu(2, 2)))
void recurrence(const _Float16* __restrict__ xp,
                const float* __restrict__ bh,
                const uint32_t* __restrict__ Wp,
                float* __restrict__ hs) {
    const int wg  = blockIdx.x;            // 0..63
    const int c   = wg >> 4;               // 0..3
    const int b0  = wg & 15;               // 0..15
    const int cbP = c * 32 + b0;           // pair P
    const int cbQ = cbP + 16;              // pair Q (same c -> same weights)
    const int tid = threadIdx.x;           // 0..511
    const int lane = tid & 63;
    const int vs = lane & 7;
    const int uq = lane >> 3;
    const int wv = tid >> 6;               // 0..7
    const int up0 = wv * 8 + uq;           // 0..63 ; B-set upair = up0+64
    const int u0 = up0 * 2;                // B-set u = u0+128

    // per-pair h double buffer: 2 x (8 slices x 20 words), stride-20 banks
    __shared__ __align__(16) uint32_t h2sP[2][160];
    __shared__ __align__(16) uint32_t h2sQ[2][160];

    // 32 named uint4 weights = 128 half2 (A-set = wp thread tid, B-set =
    // wp thread tid+512). Shared between pairs P and Q (same c).
    const uint4* wb = (const uint4*)Wp + (size_t)c * 16 * 1024 + tid;
    uint4 wA00 = wb[0 * 1024],        wA01 = wb[1 * 1024],        wA02 = wb[2 * 1024],        wA03 = wb[3 * 1024];
    uint4 wA10 = wb[4 * 1024],        wA11 = wb[5 * 1024],        wA12 = wb[6 * 1024],        wA13 = wb[7 * 1024];
    uint4 wA20 = wb[8 * 1024],        wA21 = wb[9 * 1024],        wA22 = wb[10 * 1024],       wA23 = wb[11 * 1024];
    uint4 wA30 = wb[12 * 1024],       wA31 = wb[13 * 1024],       wA32 = wb[14 * 1024],       wA33 = wb[15 * 1024];
    uint4 wB00 = wb[0 * 1024 + 512],  wB01 = wb[1 * 1024 + 512],  wB02 = wb[2 * 1024 + 512],  wB03 = wb[3 * 1024 + 512];
    uint4 wB10 = wb[4 * 1024 + 512],  wB11 = wb[5 * 1024 + 512],  wB12 = wb[6 * 1024 + 512],  wB13 = wb[7 * 1024 + 512];
    uint4 wB20 = wb[8 * 1024 + 512],  wB21 = wb[9 * 1024 + 512],  wB22 = wb[10 * 1024 + 512], wB23 = wb[11 * 1024 + 512];
    uint4 wB30 = wb[12 * 1024 + 512], wB31 = wb[13 * 1024 + 512], wB32 = wb[14 * 1024 + 512], wB33 = wb[15 * 1024 + 512];
    PIN4(wA00); PIN4(wA01); PIN4(wA02); PIN4(wA03);
    PIN4(wA10); PIN4(wA11); PIN4(wA12); PIN4(wA13);
    PIN4(wA20); PIN4(wA21); PIN4(wA22); PIN4(wA23);
    PIN4(wA30); PIN4(wA31); PIN4(wA32); PIN4(wA33);
    PIN4(wB00); PIN4(wB01); PIN4(wB02); PIN4(wB03);
    PIN4(wB10); PIN4(wB11); PIN4(wB12); PIN4(wB13);
    PIN4(wB20); PIN4(wB21); PIN4(wB22); PIN4(wB23);
    PIN4(wB30); PIN4(wB31); PIN4(wB32); PIN4(wB33);

    // bias (shared: depends on c,u only) + per-pair xp pointers (vs<4 lanes)
    float biasA = 0.f, biasB = 0.f;
    const _Float16* xpbP = nullptr;
    const _Float16* xpbQ = nullptr;
    if (vs < 4) {
        int g_sel = vs & 1, u_sel = u0 + (vs >> 1);
        biasA = bh[(c * 2 + g_sel) * 256 + u_sel];
        biasB = bh[(c * 2 + g_sel) * 256 + u_sel + 128];
        xpbP = xp + (size_t)cbP * 200 * 512 + g_sel * 256 + u_sel;
        xpbQ = xp + (size_t)cbQ * 200 * 512 + g_sel * 256 + u_sel;
    }

    float hrAP = 0.f, hrBP = 0.f;          // valid at vs==0 (u even) / vs==2 (u odd)
    float hrAQ = 0.f, hrBQ = 0.f;
    if (tid < 160) { h2sP[0][tid] = 0u; h2sQ[0][tid] = 0u; }
    __syncthreads();

    float* hsbP = hs + (size_t)cbP * 200 * 256 + u0;   // B-set at +128
    float* hsbQ = hs + (size_t)cbQ * 200 * 256 + u0;

    // xp: current step in f32, next step prefetched one step ahead
    float cAP = 0.f, cBP = 0.f, cAQ = 0.f, cBQ = 0.f;
    _Float16 nAP = (_Float16)0.f, nBP = (_Float16)0.f;
    _Float16 nAQ = (_Float16)0.f, nBQ = (_Float16)0.f;
    if (vs < 4) {
        cAP = (float)xpbP[0]; cBP = (float)xpbP[128];
        cAQ = (float)xpbQ[0]; cBQ = (float)xpbQ[128];
    }

    for (int t = 0; t < TS; t++) {
        const uint32_t* hbP = h2sP[t & 1];
        uint32_t* hnP = h2sP[(t + 1) & 1];
        const uint32_t* hbQ = h2sQ[t & 1];
        uint32_t* hnQ = h2sQ[(t + 1) & 1];

        // prefetch next step's xp (consumed after next barrier -> ~1 step
        // of latency slack; global loads stay in flight across s_barrier)
        if (vs < 4 && t + 1 < TS) {
            nAP = xpbP[(size_t)(t + 1) * 512];
            nBP = xpbP[(size_t)(t + 1) * 512 + 128];
            nAQ = xpbQ[(size_t)(t + 1) * 512];
            nBQ = xpbQ[(size_t)(t + 1) * 512 + 128];
        }

        uint4 hP0 = *(const uint4*)(hbP + vs * 20 + 0);
        uint4 hP1 = *(const uint4*)(hbP + vs * 20 + 4);
        uint4 hP2 = *(const uint4*)(hbP + vs * 20 + 8);
        uint4 hP3 = *(const uint4*)(hbP + vs * 20 + 12);
        uint4 hQ0 = *(const uint4*)(hbQ + vs * 20 + 0);
        uint4 hQ1 = *(const uint4*)(hbQ + vs * 20 + 4);
        uint4 hQ2 = *(const uint4*)(hbQ + vs * 20 + 8);
        uint4 hQ3 = *(const uint4*)(hbQ + vs * 20 + 12);

        float aAP0 = 0.f, aAP1 = 0.f, aAP2 = 0.f, aAP3 = 0.f;
        float aBP0 = 0.f, aBP1 = 0.f, aBP2 = 0.f, aBP3 = 0.f;
        float aAQ0 = 0.f, aAQ1 = 0.f, aAQ2 = 0.f, aAQ3 = 0.f;
        float aBQ0 = 0.f, aBQ1 = 0.f, aBQ2 = 0.f, aBQ3 = 0.f;
        // 16 independent chains, P/Q and A/B interleaved for ILP
        D4(aAP0, wA00, hP0) D4(aAQ0, wA00, hQ0) D4(aBP0, wB00, hP0) D4(aBQ0, wB00, hQ0)
        D4(aAP1, wA10, hP0) D4(aAQ1, wA10, hQ0) D4(aBP1, wB10, hP0) D4(aBQ1, wB10, hQ0)
        D4(aAP2, wA20, hP0) D4(aAQ2, wA20, hQ0) D4(aBP2, wB20, hP0) D4(aBQ2, wB20, hQ0)
        D4(aAP3, wA30, hP0) D4(aAQ3, wA30, hQ0) D4(aBP3, wB30, hP0) D4(aBQ3, wB30, hQ0)
        D4(aAP0, wA01, hP1) D4(aAQ0, wA01, hQ1) D4(aBP0, wB01, hP1) D4(aBQ0, wB01, hQ1)
        D4(aAP1, wA11, hP1) D4(aAQ1, wA11, hQ1) D4(aBP1, wB11, hP1) D4(aBQ1, wB11, hQ1)
        D4(aAP2, wA21, hP1) D4(aAQ2, wA21, hQ1) D4(aBP2, wB21, hP1) D4(aBQ2, wB21, hQ1)
        D4(aAP3, wA31, hP1) D4(aAQ3, wA31, hQ1) D4(aBP3, wB31, hP1) D4(aBQ3, wB31, hQ1)
        D4(aAP0, wA02, hP2) D4(aAQ0, wA02, hQ2) D4(aBP0, wB02, hP2) D4(aBQ0, wB02, hQ2)
        D4(aAP1, wA12, hP2) D4(aAQ1, wA12, hQ2) D4(aBP1, wB12, hP2) D4(aBQ1, wB12, hQ2)
        D4(aAP2, wA22, hP2) D4(aAQ2, wA22, hQ2) D4(aBP2, wB22, hP2) D4(aBQ2, wB22, hQ2)
        D4(aAP3, wA32, hP2) D4(aAQ3, wA32, hQ2) D4(aBP3, wB32, hP2) D4(aBQ3, wB32, hQ2)
        D4(aAP0, wA03, hP3) D4(aAQ0, wA03, hQ3) D4(aBP0, wB03, hP3) D4(aBQ0, wB03, hQ3)
        D4(aAP1, wA13, hP3) D4(aAQ1, wA13, hQ3) D4(aBP1, wB13, hP3) D4(aBQ1, wB13, hQ3)
        D4(aAP2, wA23, hP3) D4(aAQ2, wA23, hQ3) D4(aBP2, wB23, hP3) D4(aBQ2, wB23, hQ3)
        D4(aAP3, wA33, hP3) D4(aAQ3, wA33, hQ3) D4(aBP3, wB33, hP3) D4(aBQ3, wB33, hQ3)

        RED3(aAP0) RED3(aAP1) RED3(aAP2) RED3(aAP3)
        RED3(aBP0) RED3(aBP1) RED3(aBP2) RED3(aBP3)
        RED3(aAQ0) RED3(aAQ1) RED3(aAQ2) RED3(aAQ3)
        RED3(aBQ0) RED3(aBQ1) RED3(aBQ2) RED3(aBQ3)

        // lane vs -> acc: vs0:(u even,j) vs1:(u even,k) vs2:(u odd,j) vs3:(u odd,k)
        float sAP = (vs == 0) ? aAP0 : (vs == 1) ? aAP1 : (vs == 2) ? aAP2 : aAP3;
        float sBP = (vs == 0) ? aBP0 : (vs == 1) ? aBP1 : (vs == 2) ? aBP2 : aBP3;
        float sAQ = (vs == 0) ? aAQ0 : (vs == 1) ? aAQ1 : (vs == 2) ? aAQ2 : aAQ3;
        float sBQ = (vs == 0) ? aBQ0 : (vs == 1) ? aBQ1 : (vs == 2) ? aBQ2 : aBQ3;
        sAP += cAP + biasA;  sBP += cBP + biasB;
        sAQ += cAQ + biasA;  sBQ += cBQ + biasB;
        float gAP = 1.f / (1.f + __expf(-sAP));
        float gBP = 1.f / (1.f + __expf(-sBP));
        float gAQ = 1.f / (1.f + __expf(-sAQ));
        float gBQ = 1.f / (1.f + __expf(-sBQ));
        // gate exchange: even-vs lanes pull partner's k-gate
        float kAP = dpp_mov<0xB1>(gAP);
        float kBP = dpp_mov<0xB1>(gBP);
        float kAQ = dpp_mov<0xB1>(gAQ);
        float kBQ = dpp_mov<0xB1>(gBQ);
        float hnAP = gAP + hrAP * (1.f - gAP - kAP);   // valid vs0, vs2
        float hnBP = gBP + hrBP * (1.f - gBP - kBP);
        float hnAQ = gAQ + hrAQ * (1.f - gAQ - kAQ);
        float hnBQ = gBQ + hrBQ * (1.f - gBQ - kBQ);
        hrAP = hnAP; hrBP = hnBP; hrAQ = hnAQ; hrBQ = hnBQ;
        float h1AP = dpp_mov<0x4E>(hnAP);              // odd-u hn -> vs0
        float h1BP = dpp_mov<0x4E>(hnBP);
        float h1AQ = dpp_mov<0x4E>(hnAQ);
        float h1BQ = dpp_mov<0x4E>(hnBQ);
        if (vs == 0) {
            h2_t pAP; pAP.x = (_Float16)hnAP; pAP.y = (_Float16)h1AP;
            h2_t pBP; pBP.x = (_Float16)hnBP; pBP.y = (_Float16)h1BP;
            h2_t pAQ; pAQ.x = (_Float16)hnAQ; pAQ.y = (_Float16)h1AQ;
            h2_t pBQ; pBQ.x = (_Float16)hnBQ; pBQ.y = (_Float16)h1BQ;
            int idx0 = (up0 >> 4) * 20 + (up0 & 15);   // B-set slice = +80 words
            hnP[idx0]      = __builtin_bit_cast(uint32_t, pAP);
            hnP[idx0 + 80] = __builtin_bit_cast(uint32_t, pBP);
            hnQ[idx0]      = __builtin_bit_cast(uint32_t, pAQ);
            hnQ[idx0 + 80] = __builtin_bit_cast(uint32_t, pBQ);
            *(float2*)(hsbP + (size_t)t * 256)       = make_float2(hnAP, h1AP);
            *(float2*)(hsbP + (size_t)t * 256 + 128) = make_float2(hnBP, h1BP);
            *(float2*)(hsbQ + (size_t)t * 256)       = make_float2(hnAQ, h1AQ);
            *(float2*)(hsbQ + (size_t)t * 256 + 128) = make_float2(hnBQ, h1BQ);
        }
        // LDS-only fence: global loads/stores stay in flight across barrier
        LDS_BARRIER();
        if (vs < 4) {
            cAP = (float)nAP; cBP = (float)nBP;
            cAQ = (float)nAQ; cBQ = (float)nBQ;
        }
    }
}

// ---------------------------------------------------------------------------
// K3: oscillator expansion (memory-bound). (unchanged)
// ---------------------------------------------------------------------------
__global__ __launch_bounds__(256) void osc(const float* __restrict__ hs,
                                           float* __restrict__ out) {
    int tid = blockIdx.x * 256 + threadIdx.x;   // 1,638,400
    const int cstride = 32 * 200 * 256;
    int u = tid & 255;
    int bt = tid >> 8;
    int t = bt % 200, b = bt / 200;
    float phi   = hs[0 * cstride + tid];
    float omega = hs[1 * cstride + tid];
    float r     = hs[2 * cstride + tid];
    float mu    = hs[3 * cstride + tid];
    float* o = out + ((size_t)(b * 2000 + t * 10)) * 256 + u;
#pragma unroll
    for (int s = 0; s < 10; s++) {
        o[(size_t)s * 256] = r * __cosf(phi);
        r = r + (mu - r * r) * r;
        phi = phi + omega;
    }
}

// ---------------------------------------------------------------------------
extern "C" void kernel_launch(void* const* d_in, const int* in_sizes, int n_in,
                              void* d_out, int out_size, void* d_ws, size_t ws_size,
                              hipStream_t stream) {
    const float* x  = (const float*)d_in[0];
    const float* Wx = (const float*)d_in[1];
    const float* bx = (const float*)d_in[2];
    const float* Wh = (const float*)d_in[3];
    const float* bh = (const float*)d_in[4];
    float* out = (float*)d_out;

    char* ws = (char*)d_ws;
    const size_t XP = (size_t)4 * 32 * 200 * 512 * 2;   // 26.2 MB f16
    const size_t HS = (size_t)4 * 32 * 200 * 256 * 4;   // 26.2 MB f32
    const size_t XH = (size_t)6400 * 256 * 2;           // 3.28 MB

    _Float16* xp  = (_Float16*)ws;
    float*    hs  = (float*)(ws + XP);
    // xh/wxt alias the hs region: they are dead before recurrence writes hs.
    _Float16* xh  = (_Float16*)(ws + XP);
    _Float16* wxt = (_Float16*)(ws + XP + XH);
    uint32_t* wp  = (uint32_t*)(ws + XP + HS);

    pack_all<<<9472, 256, 0, stream>>>(x, Wx, Wh, xh, wxt, wp);
    xp_gemm<<<800, 256, 0, stream>>>(xh, wxt, bx, xp);
    recurrence<<<64, 512, 0, stream>>>(xp, bh, wp, hs);
    osc<<<6400, 256, 0, stream>>>(hs, out);
}

// Round 5
// 473.909 us; speedup vs baseline: 1.0397x; 1.0397x over previous
//
#include <hip/hip_runtime.h>
#include <hip/hip_fp16.h>
#include <stdint.h>

#define TS 200

typedef _Float16 h2_t  __attribute__((ext_vector_type(2)));
typedef _Float16 f16x8 __attribute__((ext_vector_type(8)));
typedef float    f32x4 __attribute__((ext_vector_type(4)));

template <int CTRL>
static __device__ __forceinline__ float dpp_add(float x) {
    int m = __builtin_amdgcn_update_dpp(0, __builtin_bit_cast(int, x), CTRL, 0xF, 0xF, true);
    return x + __builtin_bit_cast(float, m);
}

// ---------------------------------------------------------------------------
// K0: one-time packs.
//  blocks [0,6400):      xh[row=b*200+t][k] = f16(x[b][10t][k])        (unchanged)
//  blocks [6400,8448):   wxt[n=c*512+g*256+u][k] = f16(Wx[c][g][k][u]) (unchanged)
//  blocks [8448,10496):  wp: W_h as MFMA B-fragments for the M-batched
//    recurrence. Layout [c 4][w 8][nt 4][kt 8][lane 64][e 8] f16 (1 MB).
//    Wave w owns u-subblock ub=w*32 (both gates). n-tile nt: g=nt>>1,
//    par=nt&1 (even/odd u interleave so j,k for a unit are lane-local):
//      v_out = w*32 + 2*(lane&15) + par
//      k_in  = kt*32 + (lane>>4)*8 + e        (xp_gemm's proven B-frag map)
//      value = W_h[c][g][k_in][v_out]
// ---------------------------------------------------------------------------
__global__ __launch_bounds__(256) void pack_all(const float* __restrict__ x,
                                                const float* __restrict__ Wx,
                                                const float* __restrict__ Wh,
                                                _Float16* __restrict__ xh,
                                                _Float16* __restrict__ wxt,
                                                _Float16* __restrict__ wp) {
    int bid = blockIdx.x, tid = threadIdx.x;
    if (bid < 6400) {
        int row = bid, col = tid;
        int b = row / 200, t = row - b * 200;
        xh[(size_t)row * 256 + col] = (_Float16)x[((size_t)(b * 2000 + t * 10)) * 256 + col];
    } else if (bid < 8448) {
        int n = bid - 6400, k = tid;
        wxt[(size_t)n * 256 + k] = (_Float16)Wx[((size_t)((n >> 8) * 256 + k)) * 256 + (n & 255)];
    } else {
        int i = (bid - 8448) * 256 + tid;            // [0, 524288)
        int e  = i & 7;
        int ln = (i >> 3) & 63;
        int kt = (i >> 9) & 7;
        int nt = (i >> 12) & 3;
        int w  = (i >> 14) & 7;
        int c  = i >> 17;
        int g = nt >> 1, par = nt & 1;
        int u = w * 32 + 2 * (ln & 15) + par;        // output unit (column)
        int k = kt * 32 + (ln >> 4) * 8 + e;         // input unit (reduction)
        wp[i] = (_Float16)Wh[((size_t)((c * 2 + g) * 256 + k)) * 256 + u];
    }
}

// ---------------------------------------------------------------------------
// K1: xp = X[6400x256] * W[256x2048] + bias, f16 MFMA 16x16x32. (unchanged)
// ---------------------------------------------------------------------------
__global__ __launch_bounds__(256) void xp_gemm(const _Float16* __restrict__ xh,
                                               const _Float16* __restrict__ wxt,
                                               const float* __restrict__ bxf,
                                               _Float16* __restrict__ xp) {
    __shared__ _Float16 As[128 * 64];
    __shared__ _Float16 Bs[128 * 64];
    const int tid = threadIdx.x;
    const int lane = tid & 63, w = tid >> 6;
    const int m0 = (blockIdx.x >> 4) * 128;
    const int n0 = (blockIdx.x & 15) * 128;
    const int mw = (w & 1) * 64, nw = (w >> 1) * 64;

    f32x4 acc[4][4] = {};

    for (int kb = 0; kb < 4; kb++) {
        const int k0 = kb * 64;
#pragma unroll
        for (int q = 0; q < 4; q++) {
            int ii = w * 4 + q;
            int r = ii * 8 + (lane >> 3);
            int kcol = (lane & 7) * 8;
            const _Float16* ga = xh  + (size_t)(m0 + r) * 256 + k0 + kcol;
            const _Float16* gb = wxt + (size_t)(n0 + r) * 256 + k0 + kcol;
            __builtin_amdgcn_global_load_lds(
                (const __attribute__((address_space(1))) uint32_t*)ga,
                (__attribute__((address_space(3))) uint32_t*)(As + ii * 512), 16, 0, 0);
            __builtin_amdgcn_global_load_lds(
                (const __attribute__((address_space(1))) uint32_t*)gb,
                (__attribute__((address_space(3))) uint32_t*)(Bs + ii * 512), 16, 0, 0);
        }
        __syncthreads();
#pragma unroll
        for (int kc = 0; kc < 2; kc++) {
            f16x8 a[4], b[4];
#pragma unroll
            for (int mt = 0; mt < 4; mt++)
                a[mt] = *(const f16x8*)&As[(mw + mt * 16 + (lane & 15)) * 64 + kc * 32 + (lane >> 4) * 8];
#pragma unroll
            for (int nt = 0; nt < 4; nt++)
                b[nt] = *(const f16x8*)&Bs[(nw + nt * 16 + (lane & 15)) * 64 + kc * 32 + (lane >> 4) * 8];
#pragma unroll
            for (int mt = 0; mt < 4; mt++)
#pragma unroll
                for (int nt = 0; nt < 4; nt++)
                    acc[mt][nt] = __builtin_amdgcn_mfma_f32_16x16x32_f16(a[mt], b[nt], acc[mt][nt], 0, 0, 0);
        }
        __syncthreads();
    }

    const int nl = lane & 15, quad = lane >> 4;
#pragma unroll
    for (int nt = 0; nt < 4; nt++) {
        int n = n0 + nw + nt * 16 + nl;
        float bias = bxf[n];
        int c = n >> 9, gu = n & 511;
#pragma unroll
        for (int mt = 0; mt < 4; mt++)
#pragma unroll
            for (int r = 0; r < 4; r++) {
                int m = m0 + mw + mt * 16 + quad * 4 + r;
                int b = m / 200, t = m - b * 200;
                xp[((size_t)((c * 32 + b) * 200 + t)) * 512 + gu] =
                    (_Float16)(acc[mt][nt][r] + bias);
            }
    }
}

// ---------------------------------------------------------------------------
// K2 (R5): M-batched MFMA recurrence. 8 WGs x 512 threads; WG = (c, bb) with
// 16 batches as the MFMA M dimension. Per step: C[16 b x 512 n] =
// h(t)[16x256] * W[256x512] via mfma_f32_16x16x32_f16 (fragment maps copied
// from the proven xp_gemm). W = 32 pinned uint4/thread (128 VGPR, same budget
// as R2). h(t) in 8KB LDS [b][u'] f16, double-buffered, XOR-swizzled
// (byte ^= (b&7)<<4, Guideline 4) since lanes read different b-rows at the
// same u-columns. Gate interleave (even u = j-col pair, odd = k... per lane:
// nt0=jE nt1=jO nt2=kE nt3=kO at u={ub+2*c16, +1}) makes the gate combine
// lane-local and the h-writeback a single b32 per row. h_old stays in regs
// (writer == owner). ONE barrier serves 16 batches (R2 paid one per batch).
// ---------------------------------------------------------------------------
#define PIN4(W) asm volatile("" : "+v"(W.x), "+v"(W.y), "+v"(W.z), "+v"(W.w))

#define LDS_BARRIER()                                        \
    do {                                                     \
        __builtin_amdgcn_sched_barrier(0);                   \
        asm volatile("s_waitcnt lgkmcnt(0)" ::: "memory");   \
        __builtin_amdgcn_s_barrier();                        \
        __builtin_amdgcn_sched_barrier(0);                   \
    } while (0)

__global__ __attribute__((amdgpu_flat_work_group_size(512, 512),
                          amdgpu_waves_per_eu(2, 2)))
void recurrence(const _Float16* __restrict__ xp,
                const float* __restrict__ bh,
                const _Float16* __restrict__ Wp,
                float* __restrict__ hs) {
    const int wg  = blockIdx.x;            // 0..7
    const int c   = wg >> 1;               // channel
    const int bb  = wg & 1;                // batch block (16 b each)
    const int tid = threadIdx.x;           // 0..511
    const int lane = tid & 63;
    const int w    = tid >> 6;             // wave 0..7, owns u-subblock ub
    const int c16  = lane & 15;
    const int quad = lane >> 4;
    const int ub   = w * 32;

    // h double buffer: [2][b=16][u'=256] f16, XOR swizzle (b&7)<<4 on bytes
    __shared__ __align__(16) char hb[2][16 * 512];

    // ---- W fragments: 32 uint4 = 128 VGPR, fully unrolled const-indexed ----
    uint4 W[4][8];
    {
        const uint4* wq = (const uint4*)Wp;
        const int base = ((c * 8 + w) * 4) * 8 * 64;
#pragma unroll
        for (int nt = 0; nt < 4; nt++)
#pragma unroll
            for (int kt = 0; kt < 8; kt++)
                W[nt][kt] = wq[base + (nt * 8 + kt) * 64 + lane];
    }
#pragma unroll
    for (int nt = 0; nt < 4; nt++)
#pragma unroll
        for (int kt = 0; kt < 8; kt++) { PIN4(W[nt][kt]); }

    // ---- bias (loop-invariant), xp column offsets ----
    float bias[4];
    int   guo[4];
#pragma unroll
    for (int nt = 0; nt < 4; nt++) {
        int g = nt >> 1, par = nt & 1;
        int u = ub + 2 * c16 + par;
        bias[nt] = bh[(c * 2 + g) * 256 + u];
        guo[nt]  = g * 256 + u;
    }
    const size_t cb0 = (size_t)(c * 32 + bb * 16 + quad * 4);  // + r

    // ---- zero h(0) buffer, init ----
    ((float4*)hb[0])[tid] = make_float4(0.f, 0.f, 0.f, 0.f);
    float hE[4] = {0.f, 0.f, 0.f, 0.f};
    float hO[4] = {0.f, 0.f, 0.f, 0.f};

    // xp(0) preload
    float cur[4][4];
#pragma unroll
    for (int nt = 0; nt < 4; nt++)
#pragma unroll
        for (int r = 0; r < 4; r++)
            cur[nt][r] = (float)xp[(cb0 + r) * 102400 + guo[nt]];

    __syncthreads();

    for (int t = 0; t < TS; t++) {
        const char* rbuf = hb[t & 1];
        char* wbuf = hb[(t + 1) & 1];

        // prefetch xp(t+1); in flight across the whole step
        _Float16 nxt[4][4];
        if (t + 1 < TS) {
#pragma unroll
            for (int nt = 0; nt < 4; nt++)
#pragma unroll
                for (int r = 0; r < 4; r++)
                    nxt[nt][r] = xp[(cb0 + r) * 102400 + (size_t)(t + 1) * 512 + guo[nt]];
        }

        // ---- GEMM: acc[nt] += A(h)[16x32] * W[nt][kt], 8 k-tiles ----
        f32x4 acc[4] = {};
        const int bA = c16;                               // A row = batch
#pragma unroll
        for (int kt = 0; kt < 8; kt++) {
            int off = bA * 512 + ((kt * 64 + quad * 16) ^ ((bA & 7) << 4));
            f16x8 a = *(const f16x8*)(rbuf + off);        // ds_read_b128
#pragma unroll
            for (int nt = 0; nt < 4; nt++)
                acc[nt] = __builtin_amdgcn_mfma_f32_16x16x32_f16(
                    a, __builtin_bit_cast(f16x8, W[nt][kt]), acc[nt], 0, 0, 0);
        }

        // ---- elementwise gate combine; C row m = quad*4 + r = batch ----
#pragma unroll
        for (int r = 0; r < 4; r++) {
            float sJE = acc[0][r] + cur[0][r] + bias[0];
            float sJO = acc[1][r] + cur[1][r] + bias[1];
            float sKE = acc[2][r] + cur[2][r] + bias[2];
            float sKO = acc[3][r] + cur[3][r] + bias[3];
            float jE = 1.f / (1.f + __expf(-sJE));
            float jO = 1.f / (1.f + __expf(-sJO));
            float kE = 1.f / (1.f + __expf(-sKE));
            float kO = 1.f / (1.f + __expf(-sKO));
            float hEn = jE + hE[r] * (1.f - jE - kE);
            float hOn = jO + hO[r] * (1.f - jO - kO);
            hE[r] = hEn; hO[r] = hOn;

            // h(t+1) -> LDS (swizzled b32: pair u = ub+2*c16, +1)
            int b = quad * 4 + r;
            int woff = b * 512 + ((w * 64 + c16 * 4) ^ ((b & 7) << 4));
            h2_t p; p.x = (_Float16)hEn; p.y = (_Float16)hOn;
            *(uint32_t*)(wbuf + woff) = __builtin_bit_cast(uint32_t, p);

            // hs global store (fire-and-forget; layout unchanged for osc)
            *(float2*)(hs + (cb0 + r) * 51200 + (size_t)t * 256 + ub + 2 * c16) =
                make_float2(hEn, hOn);
        }

        // consume prefetch
        if (t + 1 < TS) {
#pragma unroll
            for (int nt = 0; nt < 4; nt++)
#pragma unroll
                for (int r = 0; r < 4; r++)
                    cur[nt][r] = (float)nxt[nt][r];
        }

        // LDS-only fence: global loads/stores stay in flight across barrier
        LDS_BARRIER();
    }
}

// ---------------------------------------------------------------------------
// K3: oscillator expansion (memory-bound). (unchanged)
// ---------------------------------------------------------------------------
__global__ __launch_bounds__(256) void osc(const float* __restrict__ hs,
                                           float* __restrict__ out) {
    int tid = blockIdx.x * 256 + threadIdx.x;   // 1,638,400
    const int cstride = 32 * 200 * 256;
    int u = tid & 255;
    int bt = tid >> 8;
    int t = bt % 200, b = bt / 200;
    float phi   = hs[0 * cstride + tid];
    float omega = hs[1 * cstride + tid];
    float r     = hs[2 * cstride + tid];
    float mu    = hs[3 * cstride + tid];
    float* o = out + ((size_t)(b * 2000 + t * 10)) * 256 + u;
#pragma unroll
    for (int s = 0; s < 10; s++) {
        o[(size_t)s * 256] = r * __cosf(phi);
        r = r + (mu - r * r) * r;
        phi = phi + omega;
    }
}

// ---------------------------------------------------------------------------
extern "C" void kernel_launch(void* const* d_in, const int* in_sizes, int n_in,
                              void* d_out, int out_size, void* d_ws, size_t ws_size,
                              hipStream_t stream) {
    const float* x  = (const float*)d_in[0];
    const float* Wx = (const float*)d_in[1];
    const float* bx = (const float*)d_in[2];
    const float* Wh = (const float*)d_in[3];
    const float* bh = (const float*)d_in[4];
    float* out = (float*)d_out;

    char* ws = (char*)d_ws;
    const size_t XP = (size_t)4 * 32 * 200 * 512 * 2;   // 26.2 MB f16
    const size_t HS = (size_t)4 * 32 * 200 * 256 * 4;   // 26.2 MB f32
    const size_t XH = (size_t)6400 * 256 * 2;           // 3.28 MB

    _Float16* xp  = (_Float16*)ws;
    float*    hs  = (float*)(ws + XP);
    // xh/wxt alias the hs region: they are dead before recurrence writes hs.
    _Float16* xh  = (_Float16*)(ws + XP);
    _Float16* wxt = (_Float16*)(ws + XP + XH);
    _Float16* wp  = (_Float16*)(ws + XP + HS);          // 1 MB (same as before)

    pack_all<<<10496, 256, 0, stream>>>(x, Wx, Wh, xh, wxt, wp);
    xp_gemm<<<800, 256, 0, stream>>>(xh, wxt, bx, xp);
    recurrence<<<8, 512, 0, stream>>>(xp, bh, wp, hs);
    osc<<<6400, 256, 0, stream>>>(hs, out);
}

// Round 6
// 375.375 us; speedup vs baseline: 1.3127x; 1.2625x over previous
//
#include <hip/hip_runtime.h>
#include <hip/hip_fp16.h>
#include <stdint.h>

#define TS 200

typedef _Float16 h2_t  __attribute__((ext_vector_type(2)));
typedef _Float16 f16x8 __attribute__((ext_vector_type(8)));
typedef float    f32x4 __attribute__((ext_vector_type(4)));

static __device__ __forceinline__ float rcpf(float x) {
#if __has_builtin(__builtin_amdgcn_rcpf)
    return __builtin_amdgcn_rcpf(x);
#else
    return 1.f / x;
#endif
}
static __device__ __forceinline__ float sigf(float s) {
    return rcpf(1.f + __expf(-s));
}

// ---------------------------------------------------------------------------
// K0: one-time packs (identical to R5).
//  blocks [0,6400):      xh[row=b*200+t][k] = f16(x[b][10t][k])
//  blocks [6400,8448):   wxt[n=c*512+g*256+u][k] = f16(Wx[c][g][k][u])
//  blocks [8448,10496):  wp: W_h as MFMA B-fragments
//    [c 4][w 8][nt 4][kt 8][lane 64][e 8] f16; g=nt>>1, par=nt&1;
//    u = w*32 + 2*(lane&15) + par ; k = kt*32 + (lane>>4)*8 + e
// ---------------------------------------------------------------------------
__global__ __launch_bounds__(256) void pack_all(const float* __restrict__ x,
                                                const float* __restrict__ Wx,
                                                const float* __restrict__ Wh,
                                                _Float16* __restrict__ xh,
                                                _Float16* __restrict__ wxt,
                                                _Float16* __restrict__ wp) {
    int bid = blockIdx.x, tid = threadIdx.x;
    if (bid < 6400) {
        int row = bid, col = tid;
        int b = row / 200, t = row - b * 200;
        xh[(size_t)row * 256 + col] = (_Float16)x[((size_t)(b * 2000 + t * 10)) * 256 + col];
    } else if (bid < 8448) {
        int n = bid - 6400, k = tid;
        wxt[(size_t)n * 256 + k] = (_Float16)Wx[((size_t)((n >> 8) * 256 + k)) * 256 + (n & 255)];
    } else {
        int i = (bid - 8448) * 256 + tid;            // [0, 524288)
        int e  = i & 7;
        int ln = (i >> 3) & 63;
        int kt = (i >> 9) & 7;
        int nt = (i >> 12) & 3;
        int w  = (i >> 14) & 7;
        int c  = i >> 17;
        int g = nt >> 1, par = nt & 1;
        int u = w * 32 + 2 * (ln & 15) + par;        // output unit (column)
        int k = kt * 32 + (ln >> 4) * 8 + e;         // input unit (reduction)
        wp[i] = (_Float16)Wh[((size_t)((c * 2 + g) * 256 + k)) * 256 + u];
    }
}

// ---------------------------------------------------------------------------
// K1: xp = X[6400x256] * W[256x2048] + bias, f16 MFMA 16x16x32.
// R6 changes: (a) output column relayout col = (u>>1)*4 + (u&1)*2 + g so the
// recurrence's 4 gate inputs per (lane,r) are one contiguous u64;
// (b) b_h folded into the bias (bias = bx[n] + bh[n]) so the recurrence
// adds nothing.
// ---------------------------------------------------------------------------
__global__ __launch_bounds__(256) void xp_gemm(const _Float16* __restrict__ xh,
                                               const _Float16* __restrict__ wxt,
                                               const float* __restrict__ bxf,
                                               const float* __restrict__ bhf,
                                               _Float16* __restrict__ xp) {
    __shared__ _Float16 As[128 * 64];
    __shared__ _Float16 Bs[128 * 64];
    const int tid = threadIdx.x;
    const int lane = tid & 63, w = tid >> 6;
    const int m0 = (blockIdx.x >> 4) * 128;
    const int n0 = (blockIdx.x & 15) * 128;
    const int mw = (w & 1) * 64, nw = (w >> 1) * 64;

    f32x4 acc[4][4] = {};

    for (int kb = 0; kb < 4; kb++) {
        const int k0 = kb * 64;
#pragma unroll
        for (int q = 0; q < 4; q++) {
            int ii = w * 4 + q;
            int r = ii * 8 + (lane >> 3);
            int kcol = (lane & 7) * 8;
            const _Float16* ga = xh  + (size_t)(m0 + r) * 256 + k0 + kcol;
            const _Float16* gb = wxt + (size_t)(n0 + r) * 256 + k0 + kcol;
            __builtin_amdgcn_global_load_lds(
                (const __attribute__((address_space(1))) uint32_t*)ga,
                (__attribute__((address_space(3))) uint32_t*)(As + ii * 512), 16, 0, 0);
            __builtin_amdgcn_global_load_lds(
                (const __attribute__((address_space(1))) uint32_t*)gb,
                (__attribute__((address_space(3))) uint32_t*)(Bs + ii * 512), 16, 0, 0);
        }
        __syncthreads();
#pragma unroll
        for (int kc = 0; kc < 2; kc++) {
            f16x8 a[4], b[4];
#pragma unroll
            for (int mt = 0; mt < 4; mt++)
                a[mt] = *(const f16x8*)&As[(mw + mt * 16 + (lane & 15)) * 64 + kc * 32 + (lane >> 4) * 8];
#pragma unroll
            for (int nt = 0; nt < 4; nt++)
                b[nt] = *(const f16x8*)&Bs[(nw + nt * 16 + (lane & 15)) * 64 + kc * 32 + (lane >> 4) * 8];
#pragma unroll
            for (int mt = 0; mt < 4; mt++)
#pragma unroll
                for (int nt = 0; nt < 4; nt++)
                    acc[mt][nt] = __builtin_amdgcn_mfma_f32_16x16x32_f16(a[mt], b[nt], acc[mt][nt], 0, 0, 0);
        }
        __syncthreads();
    }

    const int nl = lane & 15, quad = lane >> 4;
#pragma unroll
    for (int nt = 0; nt < 4; nt++) {
        int n = n0 + nw + nt * 16 + nl;
        float bias = bxf[n] + bhf[n];            // b_h folded in (layout matches)
        int c = n >> 9;
        int gu = n & 511;
        int g = gu >> 8, u = gu & 255;
        int col = ((u >> 1) << 2) + ((u & 1) << 1) + g;   // packed gate quad
#pragma unroll
        for (int mt = 0; mt < 4; mt++)
#pragma unroll
            for (int r = 0; r < 4; r++) {
                int m = m0 + mw + mt * 16 + quad * 4 + r;
                int b = m / 200, t = m - b * 200;
                xp[((size_t)((c * 32 + b) * 200 + t)) * 512 + col] =
                    (_Float16)(acc[mt][nt][r] + bias);
            }
    }
}

// ---------------------------------------------------------------------------
// K2 (R6): M-batched MFMA recurrence, VALU-debloated. Structure = R5 (8 WGs
// x 512 thr, 16-batch M, W in 128 pinned VGPRs, 8KB dbuf swizzled h in LDS,
// LDS-only barrier). R5 PMC: active-CU VALUBusy 73% -> VALU-issue-bound with
// ~2.6x inst bloat (reg-cap spills at VGPR=256 + 16 scalar xp loads).
// Fixes: 4 u64 xp loads via packed layout + pointer strength-reduction;
// bias folded into xp; branch-free prefetch; packed cur/nxt; rcp sigmoid.
// Est. live regs ~210 < 256 cap -> no spills.
// ---------------------------------------------------------------------------
#define PIN4(W) asm volatile("" : "+v"(W.x), "+v"(W.y), "+v"(W.z), "+v"(W.w))

#define LDS_BARRIER()                                        \
    do {                                                     \
        __builtin_amdgcn_sched_barrier(0);                   \
        asm volatile("s_waitcnt lgkmcnt(0)" ::: "memory");   \
        __builtin_amdgcn_s_barrier();                        \
        __builtin_amdgcn_sched_barrier(0);                   \
    } while (0)

__global__ __attribute__((amdgpu_flat_work_group_size(512, 512),
                          amdgpu_waves_per_eu(2, 2)))
void recurrence(const _Float16* __restrict__ xp,
                const _Float16* __restrict__ Wp,
                float* __restrict__ hs) {
    const int wg  = blockIdx.x;            // 0..7
    const int c   = wg >> 1;               // channel
    const int bb  = wg & 1;                // batch block (16 b each)
    const int tid = threadIdx.x;           // 0..511
    const int lane = tid & 63;
    const int w    = tid >> 6;             // wave 0..7, owns u-subblock ub
    const int c16  = lane & 15;
    const int quad = lane >> 4;
    const int ub   = w * 32;

    // h double buffer: [2][b=16][u'=256] f16, XOR swizzle (b&7)<<4 on bytes
    __shared__ __align__(16) char hb[2][16 * 512];

    // ---- W fragments: 32 uint4 = 128 VGPR (identical map to R5) ----
    uint4 W[4][8];
    {
        const uint4* wq = (const uint4*)Wp;
        const int base = ((c * 8 + w) * 4) * 8 * 64;
#pragma unroll
        for (int nt = 0; nt < 4; nt++)
#pragma unroll
            for (int kt = 0; kt < 8; kt++)
                W[nt][kt] = wq[base + (nt * 8 + kt) * 64 + lane];
    }
#pragma unroll
    for (int nt = 0; nt < 4; nt++)
#pragma unroll
        for (int kt = 0; kt < 8; kt++) { PIN4(W[nt][kt]); }

    // ---- strength-reduced pointers ----
    const size_t cb0 = (size_t)(c * 32 + bb * 16 + quad * 4);  // + r
    const int xcol = (w * 16 + c16) * 4;                       // packed col base
    const _Float16* xq0 = xp + (cb0 + 0) * 102400 + xcol;
    const _Float16* xq1 = xp + (cb0 + 1) * 102400 + xcol;
    const _Float16* xq2 = xp + (cb0 + 2) * 102400 + xcol;
    const _Float16* xq3 = xp + (cb0 + 3) * 102400 + xcol;
    float* hp0 = hs + (cb0 + 0) * 51200 + ub + 2 * c16;
    float* hp1 = hs + (cb0 + 1) * 51200 + ub + 2 * c16;
    float* hp2 = hs + (cb0 + 2) * 51200 + ub + 2 * c16;
    float* hp3 = hs + (cb0 + 3) * 51200 + ub + 2 * c16;

    // ---- loop-invariant LDS offsets (read: swizzled A rows; write: h) ----
    int roff[8];
#pragma unroll
    for (int kt = 0; kt < 8; kt++)
        roff[kt] = c16 * 512 + ((kt * 64 + quad * 16) ^ ((c16 & 7) << 4));
    int woff[4];
#pragma unroll
    for (int r = 0; r < 4; r++) {
        int b = quad * 4 + r;
        woff[r] = b * 512 + ((w * 64 + c16 * 4) ^ ((b & 7) << 4));
    }

    // ---- init ----
    ((float4*)hb[0])[tid] = make_float4(0.f, 0.f, 0.f, 0.f);
    float hE0 = 0.f, hE1 = 0.f, hE2 = 0.f, hE3 = 0.f;
    float hO0 = 0.f, hO1 = 0.f, hO2 = 0.f, hO3 = 0.f;

    uint2 c0 = *(const uint2*)xq0;        // t=0 gate quads {jE,kE | jO,kO}
    uint2 c1 = *(const uint2*)xq1;
    uint2 c2 = *(const uint2*)xq2;
    uint2 c3 = *(const uint2*)xq3;

    __syncthreads();

    for (int t = 0; t < TS; t++) {
        const char* rbuf = hb[t & 1];
        char* wbuf = hb[(t + 1) & 1];

        // branch-free prefetch of step t+1 (last iter reads 1KB past xp into
        // live workspace; values unused)
        uint2 n0 = *(const uint2*)(xq0 + 512);
        uint2 n1 = *(const uint2*)(xq1 + 512);
        uint2 n2 = *(const uint2*)(xq2 + 512);
        uint2 n3 = *(const uint2*)(xq3 + 512);

        // ---- GEMM: acc[nt] += A(h)[16x32] * W[nt][kt], 8 k-tiles ----
        f32x4 a0 = {}, a1 = {}, a2 = {}, a3 = {};
#pragma unroll
        for (int kt = 0; kt < 8; kt++) {
            f16x8 av = *(const f16x8*)(rbuf + roff[kt]);  // ds_read_b128
            a0 = __builtin_amdgcn_mfma_f32_16x16x32_f16(av, __builtin_bit_cast(f16x8, W[0][kt]), a0, 0, 0, 0);
            a1 = __builtin_amdgcn_mfma_f32_16x16x32_f16(av, __builtin_bit_cast(f16x8, W[1][kt]), a1, 0, 0, 0);
            a2 = __builtin_amdgcn_mfma_f32_16x16x32_f16(av, __builtin_bit_cast(f16x8, W[2][kt]), a2, 0, 0, 0);
            a3 = __builtin_amdgcn_mfma_f32_16x16x32_f16(av, __builtin_bit_cast(f16x8, W[3][kt]), a3, 0, 0, 0);
        }

        // ---- elementwise per C row r (batch = quad*4+r); bias pre-folded ----
#define STEP_R(R, CR, HE, HO, HPR)                                      \
        {                                                               \
            h2_t lo = __builtin_bit_cast(h2_t, CR.x);                   \
            h2_t hi = __builtin_bit_cast(h2_t, CR.y);                   \
            float jE = sigf(a0[R] + (float)lo.x);                       \
            float kE = sigf(a2[R] + (float)lo.y);                       \
            float jO = sigf(a1[R] + (float)hi.x);                       \
            float kO = sigf(a3[R] + (float)hi.y);                       \
            float hEn = fmaf(HE, 1.f - jE - kE, jE);                    \
            float hOn = fmaf(HO, 1.f - jO - kO, jO);                    \
            HE = hEn; HO = hOn;                                         \
            h2_t p; p.x = (_Float16)hEn; p.y = (_Float16)hOn;           \
            *(uint32_t*)(wbuf + woff[R]) = __builtin_bit_cast(uint32_t, p); \
            *(float2*)HPR = make_float2(hEn, hOn);                      \
        }
        STEP_R(0, c0, hE0, hO0, hp0)
        STEP_R(1, c1, hE1, hO1, hp1)
        STEP_R(2, c2, hE2, hO2, hp2)
        STEP_R(3, c3, hE3, hO3, hp3)
#undef STEP_R

        // consume prefetch, advance pointers
        c0 = n0; c1 = n1; c2 = n2; c3 = n3;
        xq0 += 512; xq1 += 512; xq2 += 512; xq3 += 512;
        hp0 += 256; hp1 += 256; hp2 += 256; hp3 += 256;

        // LDS-only fence: global loads/stores stay in flight across barrier
        LDS_BARRIER();
    }
}

// ---------------------------------------------------------------------------
// K3: oscillator expansion (memory-bound). (unchanged)
// ---------------------------------------------------------------------------
__global__ __launch_bounds__(256) void osc(const float* __restrict__ hs,
                                           float* __restrict__ out) {
    int tid = blockIdx.x * 256 + threadIdx.x;   // 1,638,400
    const int cstride = 32 * 200 * 256;
    int u = tid & 255;
    int bt = tid >> 8;
    int t = bt % 200, b = bt / 200;
    float phi   = hs[0 * cstride + tid];
    float omega = hs[1 * cstride + tid];
    float r     = hs[2 * cstride + tid];
    float mu    = hs[3 * cstride + tid];
    float* o = out + ((size_t)(b * 2000 + t * 10)) * 256 + u;
#pragma unroll
    for (int s = 0; s < 10; s++) {
        o[(size_t)s * 256] = r * __cosf(phi);
        r = r + (mu - r * r) * r;
        phi = phi + omega;
    }
}

// ---------------------------------------------------------------------------
extern "C" void kernel_launch(void* const* d_in, const int* in_sizes, int n_in,
                              void* d_out, int out_size, void* d_ws, size_t ws_size,
                              hipStream_t stream) {
    const float* x  = (const float*)d_in[0];
    const float* Wx = (const float*)d_in[1];
    const float* bx = (const float*)d_in[2];
    const float* Wh = (const float*)d_in[3];
    const float* bh = (const float*)d_in[4];
    float* out = (float*)d_out;

    char* ws = (char*)d_ws;
    const size_t XP = (size_t)4 * 32 * 200 * 512 * 2;   // 26.2 MB f16
    const size_t HS = (size_t)4 * 32 * 200 * 256 * 4;   // 26.2 MB f32
    const size_t XH = (size_t)6400 * 256 * 2;           // 3.28 MB

    _Float16* xp  = (_Float16*)ws;
    float*    hs  = (float*)(ws + XP);
    // xh/wxt alias the hs region: they are dead before recurrence writes hs.
    _Float16* xh  = (_Float16*)(ws + XP);
    _Float16* wxt = (_Float16*)(ws + XP + XH);
    _Float16* wp  = (_Float16*)(ws + XP + HS);          // 1 MB

    pack_all<<<10496, 256, 0, stream>>>(x, Wx, Wh, xh, wxt, wp);
    xp_gemm<<<800, 256, 0, stream>>>(xh, wxt, bx, bh, xp);
    recurrence<<<8, 512, 0, stream>>>(xp, wp, hs);
    osc<<<6400, 256, 0, stream>>>(hs, out);
}

// Round 7
// 369.752 us; speedup vs baseline: 1.3326x; 1.0152x over previous
//
#include <hip/hip_runtime.h>
#include <hip/hip_fp16.h>
#include <stdint.h>

#define TS 200

typedef _Float16 h2_t  __attribute__((ext_vector_type(2)));
typedef _Float16 f16x8 __attribute__((ext_vector_type(8)));
typedef float    f32x4 __attribute__((ext_vector_type(4)));

static __device__ __forceinline__ float rcpf(float x) {
#if __has_builtin(__builtin_amdgcn_rcpf)
    return __builtin_amdgcn_rcpf(x);
#else
    return 1.f / x;
#endif
}
static __device__ __forceinline__ float sigf(float s) {
    return rcpf(1.f + __expf(-s));
}

// ---------------------------------------------------------------------------
// K0: one-time packs (identical to R5/R6).
//  blocks [0,6400):      xh[row=b*200+t][k] = f16(x[b][10t][k])
//  blocks [6400,8448):   wxt[n=c*512+g*256+u][k] = f16(Wx[c][g][k][u])
//  blocks [8448,10496):  wp: W_h as MFMA B-fragments
//    [c 4][w 8][nt 4][kt 8][lane 64][e 8] f16; g=nt>>1, par=nt&1;
//    u = w*32 + 2*(lane&15) + par ; k = kt*32 + (lane>>4)*8 + e
// ---------------------------------------------------------------------------
__global__ __launch_bounds__(256) void pack_all(const float* __restrict__ x,
                                                const float* __restrict__ Wx,
                                                const float* __restrict__ Wh,
                                                _Float16* __restrict__ xh,
                                                _Float16* __restrict__ wxt,
                                                _Float16* __restrict__ wp) {
    int bid = blockIdx.x, tid = threadIdx.x;
    if (bid < 6400) {
        int row = bid, col = tid;
        int b = row / 200, t = row - b * 200;
        xh[(size_t)row * 256 + col] = (_Float16)x[((size_t)(b * 2000 + t * 10)) * 256 + col];
    } else if (bid < 8448) {
        int n = bid - 6400, k = tid;
        wxt[(size_t)n * 256 + k] = (_Float16)Wx[((size_t)((n >> 8) * 256 + k)) * 256 + (n & 255)];
    } else {
        int i = (bid - 8448) * 256 + tid;            // [0, 524288)
        int e  = i & 7;
        int ln = (i >> 3) & 63;
        int kt = (i >> 9) & 7;
        int nt = (i >> 12) & 3;
        int w  = (i >> 14) & 7;
        int c  = i >> 17;
        int g = nt >> 1, par = nt & 1;
        int u = w * 32 + 2 * (ln & 15) + par;        // output unit (column)
        int k = kt * 32 + (ln >> 4) * 8 + e;         // input unit (reduction)
        wp[i] = (_Float16)Wh[((size_t)((c * 2 + g) * 256 + k)) * 256 + u];
    }
}

// ---------------------------------------------------------------------------
// K1: xp = X[6400x256] * W[256x2048] + bias, f16 MFMA 16x16x32. (R6 layout:
// packed gate-quad columns, b_h folded into bias.)
// ---------------------------------------------------------------------------
__global__ __launch_bounds__(256) void xp_gemm(const _Float16* __restrict__ xh,
                                               const _Float16* __restrict__ wxt,
                                               const float* __restrict__ bxf,
                                               const float* __restrict__ bhf,
                                               _Float16* __restrict__ xp) {
    __shared__ _Float16 As[128 * 64];
    __shared__ _Float16 Bs[128 * 64];
    const int tid = threadIdx.x;
    const int lane = tid & 63, w = tid >> 6;
    const int m0 = (blockIdx.x >> 4) * 128;
    const int n0 = (blockIdx.x & 15) * 128;
    const int mw = (w & 1) * 64, nw = (w >> 1) * 64;

    f32x4 acc[4][4] = {};

    for (int kb = 0; kb < 4; kb++) {
        const int k0 = kb * 64;
#pragma unroll
        for (int q = 0; q < 4; q++) {
            int ii = w * 4 + q;
            int r = ii * 8 + (lane >> 3);
            int kcol = (lane & 7) * 8;
            const _Float16* ga = xh  + (size_t)(m0 + r) * 256 + k0 + kcol;
            const _Float16* gb = wxt + (size_t)(n0 + r) * 256 + k0 + kcol;
            __builtin_amdgcn_global_load_lds(
                (const __attribute__((address_space(1))) uint32_t*)ga,
                (__attribute__((address_space(3))) uint32_t*)(As + ii * 512), 16, 0, 0);
            __builtin_amdgcn_global_load_lds(
                (const __attribute__((address_space(1))) uint32_t*)gb,
                (__attribute__((address_space(3))) uint32_t*)(Bs + ii * 512), 16, 0, 0);
        }
        __syncthreads();
#pragma unroll
        for (int kc = 0; kc < 2; kc++) {
            f16x8 a[4], b[4];
#pragma unroll
            for (int mt = 0; mt < 4; mt++)
                a[mt] = *(const f16x8*)&As[(mw + mt * 16 + (lane & 15)) * 64 + kc * 32 + (lane >> 4) * 8];
#pragma unroll
            for (int nt = 0; nt < 4; nt++)
                b[nt] = *(const f16x8*)&Bs[(nw + nt * 16 + (lane & 15)) * 64 + kc * 32 + (lane >> 4) * 8];
#pragma unroll
            for (int mt = 0; mt < 4; mt++)
#pragma unroll
                for (int nt = 0; nt < 4; nt++)
                    acc[mt][nt] = __builtin_amdgcn_mfma_f32_16x16x32_f16(a[mt], b[nt], acc[mt][nt], 0, 0, 0);
        }
        __syncthreads();
    }

    const int nl = lane & 15, quad = lane >> 4;
#pragma unroll
    for (int nt = 0; nt < 4; nt++) {
        int n = n0 + nw + nt * 16 + nl;
        float bias = bxf[n] + bhf[n];            // b_h folded in (layout matches)
        int c = n >> 9;
        int gu = n & 511;
        int g = gu >> 8, u = gu & 255;
        int col = ((u >> 1) << 2) + ((u & 1) << 1) + g;   // packed gate quad
#pragma unroll
        for (int mt = 0; mt < 4; mt++)
#pragma unroll
            for (int r = 0; r < 4; r++) {
                int m = m0 + mw + mt * 16 + quad * 4 + r;
                int b = m / 200, t = m - b * 200;
                xp[((size_t)((c * 32 + b) * 200 + t)) * 512 + col] =
                    (_Float16)(acc[mt][nt][r] + bias);
            }
    }
}

// ---------------------------------------------------------------------------
// K2 (R7): R6 structure + de-lockstep scheduling. R6 PMC: step 2748cy =
// MFMA pipe ~1000 + VALU ~690 + LDS pipe ~870 + ~1000 exposed latency from
// lockstep phases (all 8 waves read-burst, then mfma-burst, then ew-burst).
// Changes (maps/sync identical):
//  1. kt ROTATION: wave w walks k-tiles (w, w+1, ...). First read = own
//     just-written slice; post-barrier bursts spread over 8 LDS rows.
//     Rotation applied at W-LOAD time so hot-loop W[nt][j] stays
//     compile-time-indexed (no scratch, rule #20).
//  2. Depth-1 read pipeline: read kt j+1 while mfma-ing kt j.
//  3. Pre-barrier path cleared: prefetch-consume (vmcnt wait) + hs global
//     stores moved AFTER the barrier.
// ---------------------------------------------------------------------------
#define PIN4(W) asm volatile("" : "+v"(W.x), "+v"(W.y), "+v"(W.z), "+v"(W.w))

#define LDS_BARRIER()                                        \
    do {                                                     \
        __builtin_amdgcn_sched_barrier(0);                   \
        asm volatile("s_waitcnt lgkmcnt(0)" ::: "memory");   \
        __builtin_amdgcn_s_barrier();                        \
        __builtin_amdgcn_sched_barrier(0);                   \
    } while (0)

__global__ __attribute__((amdgpu_flat_work_group_size(512, 512),
                          amdgpu_waves_per_eu(2, 2)))
void recurrence(const _Float16* __restrict__ xp,
                const _Float16* __restrict__ Wp,
                float* __restrict__ hs) {
    const int wg  = blockIdx.x;            // 0..7
    const int c   = wg >> 1;               // channel
    const int bb  = wg & 1;                // batch block (16 b each)
    const int tid = threadIdx.x;           // 0..511
    const int lane = tid & 63;
    const int w    = tid >> 6;             // wave 0..7, owns u-subblock ub
    const int c16  = lane & 15;
    const int quad = lane >> 4;
    const int ub   = w * 32;

    // h double buffer: [2][b=16][u'=256] f16, XOR swizzle (b&7)<<4 on bytes
    __shared__ __align__(16) char hb[2][16 * 512];

    // ---- W fragments, PRE-ROTATED by wave id: W[nt][j] = mem[nt][(j+w)&7] ----
    uint4 W[4][8];
    {
        const uint4* wq = (const uint4*)Wp;
        const int base = ((c * 8 + w) * 4) * 8 * 64;
#pragma unroll
        for (int nt = 0; nt < 4; nt++)
#pragma unroll
            for (int j = 0; j < 8; j++)
                W[nt][j] = wq[base + (nt * 8 + ((j + w) & 7)) * 64 + lane];
    }
#pragma unroll
    for (int nt = 0; nt < 4; nt++)
#pragma unroll
        for (int j = 0; j < 8; j++) { PIN4(W[nt][j]); }

    // ---- strength-reduced pointers ----
    const size_t cb0 = (size_t)(c * 32 + bb * 16 + quad * 4);  // + r
    const int xcol = (w * 16 + c16) * 4;                       // packed col base
    const _Float16* xq0 = xp + (cb0 + 0) * 102400 + xcol;
    const _Float16* xq1 = xp + (cb0 + 1) * 102400 + xcol;
    const _Float16* xq2 = xp + (cb0 + 2) * 102400 + xcol;
    const _Float16* xq3 = xp + (cb0 + 3) * 102400 + xcol;
    float* hp0 = hs + (cb0 + 0) * 51200 + ub + 2 * c16;
    float* hp1 = hs + (cb0 + 1) * 51200 + ub + 2 * c16;
    float* hp2 = hs + (cb0 + 2) * 51200 + ub + 2 * c16;
    float* hp3 = hs + (cb0 + 3) * 51200 + ub + 2 * c16;

    // ---- loop-invariant LDS offsets, rotated read order (const-indexed) ----
    int roff[8];
#pragma unroll
    for (int j = 0; j < 8; j++) {
        int kt = (j + w) & 7;
        roff[j] = c16 * 512 + ((kt * 64 + quad * 16) ^ ((c16 & 7) << 4));
    }
    int woff[4];
#pragma unroll
    for (int r = 0; r < 4; r++) {
        int b = quad * 4 + r;
        woff[r] = b * 512 + ((w * 64 + c16 * 4) ^ ((b & 7) << 4));
    }

    // ---- init ----
    ((float4*)hb[0])[tid] = make_float4(0.f, 0.f, 0.f, 0.f);
    float hE0 = 0.f, hE1 = 0.f, hE2 = 0.f, hE3 = 0.f;
    float hO0 = 0.f, hO1 = 0.f, hO2 = 0.f, hO3 = 0.f;

    uint2 c0 = *(const uint2*)xq0;        // t=0 gate quads {jE,kE | jO,kO}
    uint2 c1 = *(const uint2*)xq1;
    uint2 c2 = *(const uint2*)xq2;
    uint2 c3 = *(const uint2*)xq3;

    __syncthreads();

    for (int t = 0; t < TS; t++) {
        const char* rbuf = hb[t & 1];
        char* wbuf = hb[(t + 1) & 1];

        // issue prefetch of step t+1 (branch-free; last iter reads 1KB past
        // xp into live workspace, values unused). In flight across the step.
        uint2 n0 = *(const uint2*)(xq0 + 512);
        uint2 n1 = *(const uint2*)(xq1 + 512);
        uint2 n2 = *(const uint2*)(xq2 + 512);
        uint2 n3 = *(const uint2*)(xq3 + 512);

        // ---- GEMM, rotated kt order + depth-1 read pipeline ----
        f32x4 a0 = {}, a1 = {}, a2 = {}, a3 = {};
        f16x8 av = *(const f16x8*)(rbuf + roff[0]);   // own slice first
#pragma unroll
        for (int j = 0; j < 8; j++) {
            f16x8 avn = av;
            if (j < 7) avn = *(const f16x8*)(rbuf + roff[j + 1]);
            a0 = __builtin_amdgcn_mfma_f32_16x16x32_f16(av, __builtin_bit_cast(f16x8, W[0][j]), a0, 0, 0, 0);
            a1 = __builtin_amdgcn_mfma_f32_16x16x32_f16(av, __builtin_bit_cast(f16x8, W[1][j]), a1, 0, 0, 0);
            a2 = __builtin_amdgcn_mfma_f32_16x16x32_f16(av, __builtin_bit_cast(f16x8, W[2][j]), a2, 0, 0, 0);
            a3 = __builtin_amdgcn_mfma_f32_16x16x32_f16(av, __builtin_bit_cast(f16x8, W[3][j]), a3, 0, 0, 0);
            av = avn;
        }

        // ---- elementwise per C row r (batch = quad*4+r); bias pre-folded ----
#define STEP_R(R, CR, HE, HO)                                           \
        {                                                               \
            h2_t lo = __builtin_bit_cast(h2_t, CR.x);                   \
            h2_t hi = __builtin_bit_cast(h2_t, CR.y);                   \
            float jE = sigf(a0[R] + (float)lo.x);                       \
            float kE = sigf(a2[R] + (float)lo.y);                       \
            float jO = sigf(a1[R] + (float)hi.x);                       \
            float kO = sigf(a3[R] + (float)hi.y);                       \
            float hEn = fmaf(HE, 1.f - jE - kE, jE);                    \
            float hOn = fmaf(HO, 1.f - jO - kO, jO);                    \
            HE = hEn; HO = hOn;                                         \
            h2_t p; p.x = (_Float16)hEn; p.y = (_Float16)hOn;           \
            *(uint32_t*)(wbuf + woff[R]) = __builtin_bit_cast(uint32_t, p); \
        }
        STEP_R(0, c0, hE0, hO0)
        STEP_R(1, c1, hE1, hO1)
        STEP_R(2, c2, hE2, hO2)
        STEP_R(3, c3, hE3, hO3)
#undef STEP_R

        // LDS-only fence; global loads/stores stay in flight across barrier
        LDS_BARRIER();

        // post-barrier: hs stores (reg-sourced, fire-and-forget) + consume
        *(float2*)hp0 = make_float2(hE0, hO0);
        *(float2*)hp1 = make_float2(hE1, hO1);
        *(float2*)hp2 = make_float2(hE2, hO2);
        *(float2*)hp3 = make_float2(hE3, hO3);
        c0 = n0; c1 = n1; c2 = n2; c3 = n3;
        xq0 += 512; xq1 += 512; xq2 += 512; xq3 += 512;
        hp0 += 256; hp1 += 256; hp2 += 256; hp3 += 256;
    }
}

// ---------------------------------------------------------------------------
// K3: oscillator expansion (memory-bound). (unchanged)
// ---------------------------------------------------------------------------
__global__ __launch_bounds__(256) void osc(const float* __restrict__ hs,
                                           float* __restrict__ out) {
    int tid = blockIdx.x * 256 + threadIdx.x;   // 1,638,400
    const int cstride = 32 * 200 * 256;
    int u = tid & 255;
    int bt = tid >> 8;
    int t = bt % 200, b = bt / 200;
    float phi   = hs[0 * cstride + tid];
    float omega = hs[1 * cstride + tid];
    float r     = hs[2 * cstride + tid];
    float mu    = hs[3 * cstride + tid];
    float* o = out + ((size_t)(b * 2000 + t * 10)) * 256 + u;
#pragma unroll
    for (int s = 0; s < 10; s++) {
        o[(size_t)s * 256] = r * __cosf(phi);
        r = r + (mu - r * r) * r;
        phi = phi + omega;
    }
}

// ---------------------------------------------------------------------------
extern "C" void kernel_launch(void* const* d_in, const int* in_sizes, int n_in,
                              void* d_out, int out_size, void* d_ws, size_t ws_size,
                              hipStream_t stream) {
    const float* x  = (const float*)d_in[0];
    const float* Wx = (const float*)d_in[1];
    const float* bx = (const float*)d_in[2];
    const float* Wh = (const float*)d_in[3];
    const float* bh = (const float*)d_in[4];
    float* out = (float*)d_out;

    char* ws = (char*)d_ws;
    const size_t XP = (size_t)4 * 32 * 200 * 512 * 2;   // 26.2 MB f16
    const size_t HS = (size_t)4 * 32 * 200 * 256 * 4;   // 26.2 MB f32
    const size_t XH = (size_t)6400 * 256 * 2;           // 3.28 MB

    _Float16* xp  = (_Float16*)ws;
    float*    hs  = (float*)(ws + XP);
    // xh/wxt alias the hs region: they are dead before recurrence writes hs.
    _Float16* xh  = (_Float16*)(ws + XP);
    _Float16* wxt = (_Float16*)(ws + XP + XH);
    _Float16* wp  = (_Float16*)(ws + XP + HS);          // 1 MB

    pack_all<<<10496, 256, 0, stream>>>(x, Wx, Wh, xh, wxt, wp);
    xp_gemm<<<800, 256, 0, stream>>>(xh, wxt, bx, bh, xp);
    recurrence<<<8, 512, 0, stream>>>(xp, wp, hs);
    osc<<<6400, 256, 0, stream>>>(hs, out);
}